// Round 5
// baseline (235.649 us; speedup 1.0000x reference)
//
#include <hip/hip_runtime.h>
#include <hip/hip_bf16.h>

typedef unsigned short u16;
typedef unsigned int u32;
typedef short bf16x8 __attribute__((ext_vector_type(8)));
typedef float f32x4 __attribute__((ext_vector_type(4)));
typedef u16 u16x8 __attribute__((ext_vector_type(8)));

#define HID 1024
#define BATCH 4096
#define KTOT 2048   // concat K: [x | h_prev]
// Fragment-linear layouts: unit u = tile16*64 + kstep (kstep = k/32), 1KB per
// unit; within a unit, lane l = quad*16 + m holds elems [m][quad*8 .. +8)
// (the exact 16x16x32 A/B fragment). GEMM loads these with coalesced dwordx4.

__device__ __forceinline__ u16 f2bf(float f) {
  u32 v = __builtin_bit_cast(u32, f);
  u32 r = (v + 0x7fffu + ((v >> 16) & 1u)) >> 16;  // round-nearest-even
  return (u16)r;
}
__device__ __forceinline__ float sigmoid_fast(float x) {
  return 1.0f / (1.0f + __expf(-x));
}
__device__ __forceinline__ float tanh_fast(float x) {
  return 2.0f * sigmoid_fast(2.0f * x) - 1.0f;
}

// ---------------------------------------------------------------------------
// prep_xh: xh2 in A-fragment-linear layout from f32 x|h_prev.
// slot s = global thread id; unit = s>>6 (rowtile = unit>>6, kstep = unit&63),
// lane = s&63 (m = lane&15, quad = lane>>4). Writes 16B/lane fully coalesced;
// reads 32B/lane in 128B row segments.
// ---------------------------------------------------------------------------
__global__ __launch_bounds__(256) void prep_xh(
    const float* __restrict__ x, const float* __restrict__ hp,
    u16* __restrict__ xh2) {
  int s = blockIdx.x * 256 + threadIdx.x;
  int lane = s & 63, unit = s >> 6;
  int kstep = unit & 63, rowtile = unit >> 6;
  int m = lane & 15, quad = lane >> 4;
  int row = rowtile * 16 + m;
  int kg = kstep * 32 + quad * 8;
  const float* src = (kg < 1024) ? (x + (size_t)row * 1024 + kg)
                                 : (hp + (size_t)row * 1024 + (kg - 1024));
  f32x4 a = *(const f32x4*)(src);
  f32x4 b = *(const f32x4*)(src + 4);
  u16x8 v;
#pragma unroll
  for (int j = 0; j < 4; ++j) { v[j] = f2bf(a[j]); v[j + 4] = f2bf(b[j]); }
  *(u16x8*)(xh2 + (size_t)s * 8) = v;
}

// ---------------------------------------------------------------------------
// prep_w: f32 weights -> bt in B-fragment-linear layout, gate-interleaved:
//   n' = (h/16)*64 + g*16 + (h%16)  (ntile = n'/16; 4 consecutive ntiles of a
//   superblock are gates i,f,o,c of the same 16 hidden cols)
//   k  = which*1024 + ksrc.
// Stage 1: coalesced reads -> bf16 -> LDS (row stride 66 u16: +1-dword
//          rotation -> conflict-free column gather).
// Stage 2: column gather; each wave fills complete 1KB units (fully
//          coalesced 64x16B writes).
// ---------------------------------------------------------------------------
__global__ __launch_bounds__(256) void prep_w(
    const float* __restrict__ igx, const float* __restrict__ fgx,
    const float* __restrict__ ogx, const float* __restrict__ cgx,
    const float* __restrict__ igu, const float* __restrict__ fgu,
    const float* __restrict__ ogu, const float* __restrict__ cgu,
    u16* __restrict__ bt) {
  __shared__ u16 lds[64 * 66];
  const float* srcs[8] = {igx, fgx, ogx, cgx, igu, fgu, ogu, cgu};
  int bid = blockIdx.x;
  int m = bid >> 8;            // matrix 0..7
  int tile = bid & 255;        // 64x64 tile
  int th = tile & 15, tk = tile >> 4;
  int h0 = th << 6, k0 = tk << 6;
  int g = m & 3, which = m >> 2;
  const float* W = srcs[m] + (size_t)k0 * HID + h0;

  int t = threadIdx.x;

  // stage 1: rows k0..k0+63, cols h0..h0+63 -> LDS[k][h]
  int r1 = t >> 4;             // 0..15 (row within pass)
  int c1 = (t & 15) << 2;      // 0,4,..,60
#pragma unroll
  for (int p = 0; p < 4; ++p) {
    int row = (p << 4) + r1;
    f32x4 v = *(const f32x4*)(W + (size_t)row * HID + c1);
    u32 p0 = (u32)f2bf(v[0]) | ((u32)f2bf(v[1]) << 16);
    u32 p1 = (u32)f2bf(v[2]) | ((u32)f2bf(v[3]) << 16);
    u32* d = (u32*)&lds[row * 66 + c1];
    d[0] = p0;
    d[1] = p1;
  }
  __syncthreads();

  // stage 2: thread (nl, kc) gathers k-column for h = h0+nl, writes two 16B
  // fragment slots (kstep and kstep+1). A wave covers one full 1KB unit pair.
  int nl = t >> 2;             // 0..63 local h
  int kc = t & 3;              // quad 0..3
  int np = (((h0 + nl) >> 4) << 6) + (g << 4) + ((h0 + nl) & 15);
  int ntile = np >> 4, m16 = np & 15;
  int kstep = which * 32 + (k0 >> 5);
  size_t unit = (size_t)ntile * 64 + kstep;
  int lane16 = kc * 16 + m16;
  u16x8 a, b;
#pragma unroll
  for (int j = 0; j < 8; ++j) {
    a[j] = lds[(kc * 8 + j) * 66 + nl];
    b[j] = lds[(kc * 8 + 32 + j) * 66 + nl];
  }
  *(u16x8*)(&bt[unit * 512 + lane16 * 8]) = a;
  *(u16x8*)(&bt[(unit + 1) * 512 + lane16 * 8]) = b;
}

// ---------------------------------------------------------------------------
// lstm_gemm: fragment-direct, ZERO LDS / ZERO barriers. 128x128 block tile,
// 4 waves (2x2 of 64x64), 16x16x32 bf16 MFMA. Per 32-k iter: 4 A-frag + 4
// B-frag coalesced dwordx4 loads straight into VGPRs + 16 MFMAs. No
// __syncthreads -> no vmcnt(0) drain; loads pipeline across iterations.
// Wave's 4 n-tiles = gates i,f,o,c of the same 16 hidden cols (epilogue is
// pure per-lane math). Fused LSTM epilogue, f32 in/out.
// ---------------------------------------------------------------------------
__global__ __launch_bounds__(256, 4) void lstm_gemm(
    const u16* __restrict__ xh2, const u16* __restrict__ bt,
    const float* __restrict__ cprev,
    const float* __restrict__ ib, const float* __restrict__ fb,
    const float* __restrict__ ob, const float* __restrict__ cb,
    float* __restrict__ hout, float* __restrict__ cout) {
  int t = threadIdx.x;
  int brow = blockIdx.x, bcol = blockIdx.y;
  int w = t >> 6, l = t & 63;
  int wr = (w >> 1) * 64;          // wave row offset (elements)
  int lrow = l & 15, quad = l >> 4;

  f32x4 acc[4][4] = {};

  // A units: rowtile base = brow*8 + (w>>1)*4, + mi
  // B units: ntile  base = bcol*8 + (w&1)*4, + ni
  const u16* pA = xh2 + ((size_t)(brow * 8 + (w >> 1) * 4) * 64) * 512 + l * 8;
  const u16* pB = bt  + ((size_t)(bcol * 8 + (w & 1) * 4) * 64) * 512 + l * 8;

  for (int kt = 0; kt < 64; ++kt) {
    bf16x8 af[4], bfr[4];
#pragma unroll
    for (int i = 0; i < 4; ++i) {
      af[i]  = *(const bf16x8*)(pA + (size_t)(i * 64 + kt) * 512);
      bfr[i] = *(const bf16x8*)(pB + (size_t)(i * 64 + kt) * 512);
    }
#pragma unroll
    for (int mi = 0; mi < 4; ++mi)
#pragma unroll
      for (int ni = 0; ni < 4; ++ni)
        acc[mi][ni] = __builtin_amdgcn_mfma_f32_16x16x32_bf16(
            af[mi], bfr[ni], acc[mi][ni], 0, 0, 0);
  }

  // Epilogue: n-tiles ni = gates i,f,o,c for hidden cols hcol.
  int sb = bcol * 2 + (w & 1);
  int hcol = sb * 16 + lrow;
  float bi = ib[hcol];
  float bff = fb[hcol];
  float bo = ob[hcol];
  float bc = cb[hcol];
  int grow = brow * 128;

#pragma unroll
  for (int mi = 0; mi < 4; ++mi) {
    int row0 = grow + wr + mi * 16 + quad * 4;
#pragma unroll
    for (int r = 0; r < 4; ++r) {
      size_t idx = (size_t)(row0 + r) * HID + hcol;
      float gi = sigmoid_fast(acc[mi][0][r] + bi);
      float gf = sigmoid_fast(acc[mi][1][r] + bff);
      float go = sigmoid_fast(acc[mi][2][r] + bo);
      float gc = tanh_fast(acc[mi][3][r] + bc);
      float cp = cprev[idx];
      float cv = gf * cp + gi * gc;
      float hv = go * tanh_fast(cv);
      hout[idx] = hv;
      cout[idx] = cv;
    }
  }
}

extern "C" void kernel_launch(void* const* d_in, const int* in_sizes, int n_in,
                              void* d_out, int out_size, void* d_ws, size_t ws_size,
                              hipStream_t stream) {
  const float* x   = (const float*)d_in[0];
  const float* hp  = (const float*)d_in[1];
  const float* cp  = (const float*)d_in[2];
  const float* igx = (const float*)d_in[3];
  const float* igu = (const float*)d_in[4];
  const float* ib  = (const float*)d_in[5];
  const float* fgx = (const float*)d_in[6];
  const float* fgu = (const float*)d_in[7];
  const float* fb  = (const float*)d_in[8];
  const float* ogx = (const float*)d_in[9];
  const float* ogu = (const float*)d_in[10];
  const float* ob  = (const float*)d_in[11];
  const float* cgx = (const float*)d_in[12];
  const float* cgu = (const float*)d_in[13];
  const float* cb  = (const float*)d_in[14];

  u16* bt  = (u16*)d_ws;                        // B frags: 16 MiB
  u16* xh2 = bt + (size_t)4096 * 2048;          // A frags: 16 MiB
  float* hout = (float*)d_out;
  float* cout = hout + (size_t)BATCH * HID;

  prep_xh<<<4096, 256, 0, stream>>>(x, hp, xh2);
  prep_w<<<2048, 256, 0, stream>>>(igx, fgx, ogx, cgx, igu, fgu, ogu, cgu, bt);
  lstm_gemm<<<dim3(32, 32), 256, 0, stream>>>(xh2, bt, cp, ib, fb, ob, cb,
                                              hout, cout);
}

// Round 6
// 220.805 us; speedup vs baseline: 1.0672x; 1.0672x over previous
//
#include <hip/hip_runtime.h>
#include <hip/hip_bf16.h>

typedef unsigned short u16;
typedef unsigned int u32;
typedef short bf16x8 __attribute__((ext_vector_type(8)));
typedef float f32x4 __attribute__((ext_vector_type(4)));
typedef u16 u16x8 __attribute__((ext_vector_type(8)));

#define HID 1024
#define BATCH 4096
#define KTOT 2048   // concat K: [x | h_prev]
// Fragment-linear layouts: unit u = tile16*64 + kstep (kstep = k/32), 1KB per
// unit; within a unit, lane l = quad*16 + m holds elems [m][quad*8 .. +8)
// (the exact 16x16x32 A/B fragment). GEMM loads these with coalesced dwordx4.

__device__ __forceinline__ u16 f2bf(float f) {
  u32 v = __builtin_bit_cast(u32, f);
  u32 r = (v + 0x7fffu + ((v >> 16) & 1u)) >> 16;  // round-nearest-even
  return (u16)r;
}
__device__ __forceinline__ float sigmoid_fast(float x) {
  return 1.0f / (1.0f + __expf(-x));
}
__device__ __forceinline__ float tanh_fast(float x) {
  return 2.0f * sigmoid_fast(2.0f * x) - 1.0f;
}

// ---------------------------------------------------------------------------
// prep_xh: xh2 in A-fragment-linear layout from f32 x|h_prev.
// slot s = global thread id; unit = s>>6 (rowtile = unit>>6, kstep = unit&63),
// lane = s&63 (m = lane&15, quad = lane>>4). Writes 16B/lane fully coalesced.
// ---------------------------------------------------------------------------
__global__ __launch_bounds__(256) void prep_xh(
    const float* __restrict__ x, const float* __restrict__ hp,
    u16* __restrict__ xh2) {
  int s = blockIdx.x * 256 + threadIdx.x;
  int lane = s & 63, unit = s >> 6;
  int kstep = unit & 63, rowtile = unit >> 6;
  int m = lane & 15, quad = lane >> 4;
  int row = rowtile * 16 + m;
  int kg = kstep * 32 + quad * 8;
  const float* src = (kg < 1024) ? (x + (size_t)row * 1024 + kg)
                                 : (hp + (size_t)row * 1024 + (kg - 1024));
  f32x4 a = *(const f32x4*)(src);
  f32x4 b = *(const f32x4*)(src + 4);
  u16x8 v;
#pragma unroll
  for (int j = 0; j < 4; ++j) { v[j] = f2bf(a[j]); v[j + 4] = f2bf(b[j]); }
  *(u16x8*)(xh2 + (size_t)s * 8) = v;
}

// ---------------------------------------------------------------------------
// prep_w: f32 weights -> bt in B-fragment-linear layout, gate-interleaved:
//   n' = (h/16)*64 + g*16 + (h%16); ntile = n'/16; 4 consecutive ntiles of a
//   superblock are gates i,f,o,c of the same 16 hidden cols.
// Stage 1: coalesced reads -> bf16 -> LDS (row stride 66 u16 rotation ->
//          conflict-free column gather). Stage 2: fill 1KB fragment units.
// ---------------------------------------------------------------------------
__global__ __launch_bounds__(256) void prep_w(
    const float* __restrict__ igx, const float* __restrict__ fgx,
    const float* __restrict__ ogx, const float* __restrict__ cgx,
    const float* __restrict__ igu, const float* __restrict__ fgu,
    const float* __restrict__ ogu, const float* __restrict__ cgu,
    u16* __restrict__ bt) {
  __shared__ u16 lds[64 * 66];
  const float* srcs[8] = {igx, fgx, ogx, cgx, igu, fgu, ogu, cgu};
  int bid = blockIdx.x;
  int m = bid >> 8;            // matrix 0..7
  int tile = bid & 255;        // 64x64 tile
  int th = tile & 15, tk = tile >> 4;
  int h0 = th << 6, k0 = tk << 6;
  int g = m & 3, which = m >> 2;
  const float* W = srcs[m] + (size_t)k0 * HID + h0;

  int t = threadIdx.x;

  // stage 1: rows k0..k0+63, cols h0..h0+63 -> LDS[k][h]
  int r1 = t >> 4;             // 0..15 (row within pass)
  int c1 = (t & 15) << 2;      // 0,4,..,60
#pragma unroll
  for (int p = 0; p < 4; ++p) {
    int row = (p << 4) + r1;
    f32x4 v = *(const f32x4*)(W + (size_t)row * HID + c1);
    u32 p0 = (u32)f2bf(v[0]) | ((u32)f2bf(v[1]) << 16);
    u32 p1 = (u32)f2bf(v[2]) | ((u32)f2bf(v[3]) << 16);
    u32* d = (u32*)&lds[row * 66 + c1];
    d[0] = p0;
    d[1] = p1;
  }
  __syncthreads();

  // stage 2: thread (nl, kc) gathers k-column for h = h0+nl, writes two 16B
  // fragment slots (kstep and kstep+1).
  int nl = t >> 2;             // 0..63 local h
  int kc = t & 3;              // quad 0..3
  int np = (((h0 + nl) >> 4) << 6) + (g << 4) + ((h0 + nl) & 15);
  int ntile = np >> 4, m16 = np & 15;
  int kstep = which * 32 + (k0 >> 5);
  size_t unit = (size_t)ntile * 64 + kstep;
  int lane16 = kc * 16 + m16;
  u16x8 a, b;
#pragma unroll
  for (int j = 0; j < 8; ++j) {
    a[j] = lds[(kc * 8 + j) * 66 + nl];
    b[j] = lds[(kc * 8 + 32 + j) * 66 + nl];
  }
  *(u16x8*)(&bt[unit * 512 + lane16 * 8]) = a;
  *(u16x8*)(&bt[(unit + 1) * 512 + lane16 * 8]) = b;
}

// ---------------------------------------------------------------------------
// lstm_gemm: fragment-direct, zero LDS / zero barriers, with EXPLICIT
// REGISTER DOUBLE-BUFFERING: iteration kt issues the 8 frag loads for kt+1
// before consuming buffer kt (manually unrolled x2 so buffer indices are
// compile-time). Dependency distance = 1 full iteration -> load latency
// hidden behind ~3 waves x 16 MFMAs. 128x128 block tile, 4 waves (2x2 of
// 64x64), 16x16x32 bf16 MFMA. Fused LSTM epilogue (f32 in/out); wave's 4
// n-tiles = gates i,f,o,c of the same 16 hidden cols.
// ---------------------------------------------------------------------------
#define LOAD_FRAGS(buf, kstep_)                                              \
  {                                                                          \
    int _kk = (kstep_);                                                      \
    af[buf][0]  = *(const bf16x8*)(pA + (size_t)(0 * 64 + _kk) * 512);       \
    bfr[buf][0] = *(const bf16x8*)(pB + (size_t)(0 * 64 + _kk) * 512);       \
    bfr[buf][1] = *(const bf16x8*)(pB + (size_t)(1 * 64 + _kk) * 512);       \
    bfr[buf][2] = *(const bf16x8*)(pB + (size_t)(2 * 64 + _kk) * 512);       \
    bfr[buf][3] = *(const bf16x8*)(pB + (size_t)(3 * 64 + _kk) * 512);       \
    af[buf][1]  = *(const bf16x8*)(pA + (size_t)(1 * 64 + _kk) * 512);       \
    af[buf][2]  = *(const bf16x8*)(pA + (size_t)(2 * 64 + _kk) * 512);       \
    af[buf][3]  = *(const bf16x8*)(pA + (size_t)(3 * 64 + _kk) * 512);       \
  }

#define CONSUME_FRAGS(buf)                                                   \
  {                                                                          \
    _Pragma("unroll") for (int mi = 0; mi < 4; ++mi)                         \
        _Pragma("unroll") for (int ni = 0; ni < 4; ++ni)                     \
            acc[mi][ni] = __builtin_amdgcn_mfma_f32_16x16x32_bf16(           \
                af[buf][mi], bfr[buf][ni], acc[mi][ni], 0, 0, 0);            \
  }

__global__ __launch_bounds__(256, 3) void lstm_gemm(
    const u16* __restrict__ xh2, const u16* __restrict__ bt,
    const float* __restrict__ cprev,
    const float* __restrict__ ib, const float* __restrict__ fb,
    const float* __restrict__ ob, const float* __restrict__ cb,
    float* __restrict__ hout, float* __restrict__ cout) {
  int t = threadIdx.x;
  int brow = blockIdx.x, bcol = blockIdx.y;
  int w = t >> 6, l = t & 63;
  int wr = (w >> 1) * 64;          // wave row offset (elements)
  int lrow = l & 15, quad = l >> 4;

  f32x4 acc[4][4] = {};
  bf16x8 af[2][4], bfr[2][4];

  // A units: rowtile base = brow*8 + (w>>1)*4, + mi
  // B units: ntile  base = bcol*8 + (w&1)*4, + ni
  const u16* pA = xh2 + ((size_t)(brow * 8 + (w >> 1) * 4) * 64) * 512 + l * 8;
  const u16* pB = bt  + ((size_t)(bcol * 8 + (w & 1) * 4) * 64) * 512 + l * 8;

  LOAD_FRAGS(0, 0)
  for (int kt = 0; kt < 64; kt += 2) {
    LOAD_FRAGS(1, kt + 1)
    CONSUME_FRAGS(0)
    LOAD_FRAGS(0, (kt + 2) & 63)   // kt=62 -> wraps to 0: valid mem, unused
    CONSUME_FRAGS(1)
  }

  // Epilogue: n-tiles ni = gates i,f,o,c for hidden cols hcol.
  int sb = bcol * 2 + (w & 1);
  int hcol = sb * 16 + lrow;
  float bi = ib[hcol];
  float bff = fb[hcol];
  float bo = ob[hcol];
  float bc = cb[hcol];
  int grow = brow * 128;

#pragma unroll
  for (int mi = 0; mi < 4; ++mi) {
    int row0 = grow + wr + mi * 16 + quad * 4;
#pragma unroll
    for (int r = 0; r < 4; ++r) {
      size_t idx = (size_t)(row0 + r) * HID + hcol;
      float gi = sigmoid_fast(acc[mi][0][r] + bi);
      float gf = sigmoid_fast(acc[mi][1][r] + bff);
      float go = sigmoid_fast(acc[mi][2][r] + bo);
      float gc = tanh_fast(acc[mi][3][r] + bc);
      float cp = cprev[idx];
      float cv = gf * cp + gi * gc;
      float hv = go * tanh_fast(cv);
      hout[idx] = hv;
      cout[idx] = cv;
    }
  }
}

extern "C" void kernel_launch(void* const* d_in, const int* in_sizes, int n_in,
                              void* d_out, int out_size, void* d_ws, size_t ws_size,
                              hipStream_t stream) {
  const float* x   = (const float*)d_in[0];
  const float* hp  = (const float*)d_in[1];
  const float* cp  = (const float*)d_in[2];
  const float* igx = (const float*)d_in[3];
  const float* igu = (const float*)d_in[4];
  const float* ib  = (const float*)d_in[5];
  const float* fgx = (const float*)d_in[6];
  const float* fgu = (const float*)d_in[7];
  const float* fb  = (const float*)d_in[8];
  const float* ogx = (const float*)d_in[9];
  const float* ogu = (const float*)d_in[10];
  const float* ob  = (const float*)d_in[11];
  const float* cgx = (const float*)d_in[12];
  const float* cgu = (const float*)d_in[13];
  const float* cb  = (const float*)d_in[14];

  u16* bt  = (u16*)d_ws;                        // B frags: 8 MiB (16384 units)
  u16* xh2 = bt + (size_t)4096 * 2048;          // A frags: 8 MiB
  float* hout = (float*)d_out;
  float* cout = hout + (size_t)BATCH * HID;

  prep_xh<<<4096, 256, 0, stream>>>(x, hp, xh2);
  prep_w<<<2048, 256, 0, stream>>>(igx, fgx, ogx, cgx, igu, fgu, ogu, cgu, bt);
  lstm_gemm<<<dim3(32, 32), 256, 0, stream>>>(xh2, bt, cp, ib, fb, ob, cb,
                                              hout, cout);
}